// Round 1
// baseline (3003.513 us; speedup 1.0000x reference)
//
#include <hip/hip_runtime.h>

// BasicMotionEncoder (RAFT): B=8, H=96, W=128, CORR=324.
//   cor  = relu(conv1x1(corr, wc1, bc1))        [B,256,H,W]
//   cor  = relu(conv3x3(cor,  wc2, bc2, pad1))  [B,192,H,W]
//   flo  = relu(conv7x7(flow, wf1, bf1, pad3))  [B,128,H,W]
//   flo  = relu(conv3x3(flo,  wf2, bf2, pad1))  [B,64,H,W]
//   out  = relu(conv3x3(cat(cor,flo), wo, bo))  [B,126,H,W]
//   return cat(out, flow)                       [B,128,H,W]
//
// Round 1: fp32 direct conv, 64oc x 128px tiles, 4px x 8oc register blocking.
// Weights repacked to [Cin][k^2][Cout] once per call for coalesced LDS staging.

#define TOC 64  // output channels per block

__global__ __launch_bounds__(256) void repack_w(const float* __restrict__ src,
                                                float* __restrict__ dst,
                                                int O, int I, int K2) {
  // src: OIHW [O][I][K2]  ->  dst: [I][K2][O]
  int n = O * I * K2;
  for (int s = blockIdx.x * blockDim.x + threadIdx.x; s < n;
       s += gridDim.x * blockDim.x) {
    int t = s % K2;
    int r = s / K2;
    int i = r % I;
    int o = r / I;
    dst[(i * K2 + t) * O + o] = src[s];
  }
}

// One template for all conv layers. Tile: TOC(=64) oc x (TH*TW=128) pixels.
// 256 threads: oslot = tid>>5 (8 oc each), pslot = tid&31 (4 consecutive x each).
// XCP: padded LDS row length (XC + 1 to break bank aliasing; ==XC for 1x1).
template <int CIN, int KS, int PAD, int ICB, int TH, int TW, int XCP>
__global__ __launch_bounds__(256) void conv_relu(
    const float* __restrict__ x,    // [B][CIN][H][W]
    const float* __restrict__ wt,   // [CIN][KS*KS][Cout] (repacked)
    const float* __restrict__ bias, // [Cout]
    float* __restrict__ y,          // [B][CT][H][W], write channels coff..coff+Cout-1
    int B, int H, int W, int Cout, int CT, int coff) {
  constexpr int XR = TH + KS - 1;
  constexpr int XC = TW + KS - 1;
  constexpr int K2 = KS * KS;
  constexpr int QPR = TW / 4;  // x-quads per tile row

  __shared__ __align__(16) float sx[ICB][XR][XCP];
  __shared__ __align__(16) float sw[ICB][K2][TOC];

  const int nOC = (Cout + TOC - 1) / TOC;
  const int b = blockIdx.z / nOC;
  const int oc0 = (blockIdx.z % nOC) * TOC;
  const int x0 = blockIdx.x * TW;
  const int y0 = blockIdx.y * TH;

  const int tid = threadIdx.x;
  const int oslot = tid >> 5;  // 0..7
  const int pslot = tid & 31;  // 0..31
  const int pr = pslot / QPR;  // tile row
  const int pq = pslot % QPR;  // x-quad in row

  float acc[4][8];
#pragma unroll
  for (int p = 0; p < 4; ++p)
#pragma unroll
    for (int o = 0; o < 8; ++o) acc[p][o] = 0.f;

  for (int c0 = 0; c0 < CIN; c0 += ICB) {
    // ---- stage input tile (with zero padding at borders) ----
    constexpr int XN = ICB * XR * XC;
    for (int e = tid; e < XN; e += 256) {
      int col = e % XC;
      int t = e / XC;
      int row = t % XR;
      int ic = t / XR;
      int gy = y0 + row - PAD;
      int gx = x0 + col - PAD;
      float v = 0.f;
      if (gy >= 0 && gy < H && gx >= 0 && gx < W)
        v = x[((b * CIN + c0 + ic) * H + gy) * W + gx];
      sx[ic][row][col] = v;
    }
    // ---- stage weights [ic][tap][oc] ----
    constexpr int WN = ICB * K2 * TOC;
    for (int e = tid; e < WN; e += 256) {
      int oc = e % TOC;
      int t = e / TOC;
      int tap = t % K2;
      int ic = t / K2;
      float v = 0.f;
      if (oc0 + oc < Cout) v = wt[((c0 + ic) * K2 + tap) * Cout + oc0 + oc];
      sw[ic][tap][oc] = v;
    }
    __syncthreads();

    // ---- compute ----
#pragma unroll 1
    for (int ic = 0; ic < ICB; ++ic) {
#pragma unroll
      for (int ky = 0; ky < KS; ++ky) {
        float xr[4 + KS - 1];
        if constexpr (KS == 1) {
          const float4 v4 = *(const float4*)&sx[ic][0][pq * 4];
          xr[0] = v4.x; xr[1] = v4.y; xr[2] = v4.z; xr[3] = v4.w;
        } else {
#pragma unroll
          for (int i = 0; i < 4 + KS - 1; ++i)
            xr[i] = sx[ic][pr + ky][pq * 4 + i];
        }
#pragma unroll
        for (int kx = 0; kx < KS; ++kx) {
          const float4* wp = (const float4*)&sw[ic][ky * KS + kx][oslot * 8];
          float4 w0 = wp[0], w1 = wp[1];
          float wv[8] = {w0.x, w0.y, w0.z, w0.w, w1.x, w1.y, w1.z, w1.w};
#pragma unroll
          for (int p = 0; p < 4; ++p)
#pragma unroll
            for (int o = 0; o < 8; ++o) acc[p][o] += xr[p + kx] * wv[o];
        }
      }
    }
    __syncthreads();
  }

  // ---- epilogue: bias + relu, float4 store ----
  const int ocb = oc0 + oslot * 8;
  const int oy = y0 + pr;
  const int ox = x0 + pq * 4;
#pragma unroll
  for (int o = 0; o < 8; ++o) {
    int oc = ocb + o;
    if (oc < Cout) {
      float bv = bias[oc];
      float4 v;
      v.x = fmaxf(acc[0][o] + bv, 0.f);
      v.y = fmaxf(acc[1][o] + bv, 0.f);
      v.z = fmaxf(acc[2][o] + bv, 0.f);
      v.w = fmaxf(acc[3][o] + bv, 0.f);
      *(float4*)&y[((b * CT + coff + oc) * H + oy) * W + ox] = v;
    }
  }
}

__global__ __launch_bounds__(256) void copy_flow(const float* __restrict__ flow,
                                                 float* __restrict__ out,
                                                 int B, int HW) {
  // flow [B][2][HW] -> out[b][126+c][HW] (out has 128 channels)
  int q = HW / 4;
  int n = B * 2 * q;
  int i = blockIdx.x * blockDim.x + threadIdx.x;
  if (i < n) {
    float4 v = ((const float4*)flow)[i];
    int p = i % q;
    int t = i / q;
    int c = t % 2;
    int bb = t / 2;
    ((float4*)out)[((bb * 128 + 126 + c) * HW) / 4 + p] = v;
  }
}

extern "C" void kernel_launch(void* const* d_in, const int* in_sizes, int n_in,
                              void* d_out, int out_size, void* d_ws,
                              size_t ws_size, hipStream_t stream) {
  const float* flow = (const float*)d_in[0];
  const float* corr = (const float*)d_in[1];
  const float* wc1 = (const float*)d_in[2];
  const float* bc1 = (const float*)d_in[3];
  const float* wc2 = (const float*)d_in[4];
  const float* bc2 = (const float*)d_in[5];
  const float* wf1 = (const float*)d_in[6];
  const float* bf1 = (const float*)d_in[7];
  const float* wf2 = (const float*)d_in[8];
  const float* bf2 = (const float*)d_in[9];
  const float* wo = (const float*)d_in[10];
  const float* bo = (const float*)d_in[11];
  float* out = (float*)d_out;

  const int B = 8, H = 96, W = 128;
  const int HW = H * W;

  // workspace layout (floats):
  //   bufA: 8*256*HW (cor1, later reused for flo1)
  //   bufB: 8*256*HW (concat target: cor2 in ch 0..191, flo2 in ch 192..255)
  //   repacked weights (~0.9M floats)
  float* bufA = (float*)d_ws;
  float* bufB = bufA + (size_t)B * 256 * HW;
  float* wc1t = bufB + (size_t)B * 256 * HW;  // [324][1][256]
  float* wc2t = wc1t + 324 * 256;             // [256][9][192]
  float* wf1t = wc2t + 256 * 9 * 192;         // [2][49][128]
  float* wf2t = wf1t + 2 * 49 * 128;          // [128][9][64]
  float* wot = wf2t + 128 * 9 * 64;           // [256][9][126]

  repack_w<<<dim3(128), dim3(256), 0, stream>>>(wc1, wc1t, 256, 324, 1);
  repack_w<<<dim3(512), dim3(256), 0, stream>>>(wc2, wc2t, 192, 256, 9);
  repack_w<<<dim3(32), dim3(256), 0, stream>>>(wf1, wf1t, 128, 2, 49);
  repack_w<<<dim3(128), dim3(256), 0, stream>>>(wf2, wf2t, 64, 128, 9);
  repack_w<<<dim3(512), dim3(256), 0, stream>>>(wo, wot, 126, 256, 9);

  // conv1: 1x1, 324->256, corr -> bufA
  conv_relu<324, 1, 0, 36, 1, 128, 128>
      <<<dim3(1, 96, 8 * 4), dim3(256), 0, stream>>>(corr, wc1t, bc1, bufA, B,
                                                     H, W, 256, 256, 0);
  // conv2: 3x3 pad1, 256->192, bufA -> bufB ch 0..191
  conv_relu<256, 3, 1, 16, 8, 16, 19>
      <<<dim3(8, 12, 8 * 3), dim3(256), 0, stream>>>(bufA, wc2t, bc2, bufB, B,
                                                     H, W, 192, 256, 0);
  // convf1: 7x7 pad3, 2->128, flow -> bufA (reuse)
  conv_relu<2, 7, 3, 2, 8, 16, 23>
      <<<dim3(8, 12, 8 * 2), dim3(256), 0, stream>>>(flow, wf1t, bf1, bufA, B,
                                                     H, W, 128, 128, 0);
  // convf2: 3x3 pad1, 128->64, bufA -> bufB ch 192..255
  conv_relu<128, 3, 1, 16, 8, 16, 19>
      <<<dim3(8, 12, 8 * 1), dim3(256), 0, stream>>>(bufA, wf2t, bf2, bufB, B,
                                                     H, W, 64, 256, 192);
  // conv5: 3x3 pad1, 256->126, bufB -> out ch 0..125 (CT=128)
  conv_relu<256, 3, 1, 16, 8, 16, 19>
      <<<dim3(8, 12, 8 * 2), dim3(256), 0, stream>>>(bufB, wot, bo, out, B, H,
                                                     W, 126, 128, 0);
  // flow passthrough -> out ch 126..127
  copy_flow<<<dim3(192), dim3(256), 0, stream>>>(flow, out, B, HW);
}

// Round 2
// 673.268 us; speedup vs baseline: 4.4611x; 4.4611x over previous
//
#include <hip/hip_runtime.h>

// BasicMotionEncoder (RAFT): B=8, H=96, W=128, CORR=324.
// Round 2: bf16 MFMA implicit-GEMM for conv1/conv2/convf2/conv5 (NHWC bf16
// activations), fp32 direct conv for tiny convf1 (Cin=2, 7x7) with bf16-NHWC
// epilogue. Final tiled transpose emits fp32 NCHW + flow passthrough.

typedef __bf16 bf16x8 __attribute__((ext_vector_type(8)));
typedef float f32x4 __attribute__((ext_vector_type(4)));

__device__ __forceinline__ unsigned short f2bf(float f) {
  __bf16 h = (__bf16)f;
  return __builtin_bit_cast(unsigned short, h);
}
__device__ __forceinline__ float bf2f(unsigned short u) {
  __bf16 h = __builtin_bit_cast(__bf16, u);
  return (float)h;
}

// ---------------- weight repack: OIHW f32 -> [tap][icq][OCP][8] bf16 ----------
__global__ __launch_bounds__(256) void repack_w_bf16(
    const float* __restrict__ w, unsigned short* __restrict__ dst, int O, int I,
    int K2, int ICQ, int OCP) {
  int n = K2 * ICQ * OCP * 8;
  for (int s = blockIdx.x * 256 + threadIdx.x; s < n; s += gridDim.x * 256) {
    int j = s & 7;
    int r = s >> 3;
    int oc = r % OCP;
    r /= OCP;
    int icq = r % ICQ;
    int tap = r / ICQ;
    int ic = icq * 8 + j;
    float v = (oc < O && ic < I) ? w[((size_t)oc * I + ic) * K2 + tap] : 0.f;
    dst[s] = f2bf(v);
  }
}

// fp32 repack for convf1: OIHW -> [I][K2][O]
__global__ __launch_bounds__(256) void repack_w(const float* __restrict__ src,
                                                float* __restrict__ dst, int O,
                                                int I, int K2) {
  int n = O * I * K2;
  for (int s = blockIdx.x * blockDim.x + threadIdx.x; s < n;
       s += gridDim.x * blockDim.x) {
    int t = s % K2;
    int r = s / K2;
    int i = r % I;
    int o = r / I;
    dst[(i * K2 + t) * O + o] = src[s];
  }
}

// ------------- NCHW f32 -> NHWC bf16 (zero-padded channels) -------------------
__global__ __launch_bounds__(256) void nchw2nhwc_bf16(
    const float* __restrict__ in, unsigned short* __restrict__ outp, int C,
    int CP, int HW) {
  __shared__ float sls[64][65];
  int p0 = blockIdx.x * 64;
  int c0 = blockIdx.y * 64;
  int b = p0 / HW, hw0 = p0 % HW;
  int tid = threadIdx.x;
  for (int e = tid; e < 4096; e += 256) {
    int ch = e >> 6, px = e & 63;
    float v = 0.f;
    if (c0 + ch < C) v = in[(size_t)(b * C + c0 + ch) * HW + hw0 + px];
    sls[px][ch] = v;
  }
  __syncthreads();
  for (int e = tid; e < 512; e += 256) {
    int px = e >> 3, cc = e & 7;
    if (c0 + cc * 8 < CP) {
      unsigned short pk[8];
#pragma unroll
      for (int j = 0; j < 8; ++j) pk[j] = f2bf(sls[px][cc * 8 + j]);
      *(uint4*)&outp[(size_t)(p0 + px) * CP + c0 + cc * 8] = *(uint4*)pk;
    }
  }
}

// ------------- NHWC bf16 -> NCHW f32 (channels < CO only) ---------------------
__global__ __launch_bounds__(256) void nhwc_bf16_2nchw(
    const unsigned short* __restrict__ inp, float* __restrict__ outp, int CP,
    int CO, int CT, int HW) {
  __shared__ float sls[64][65];
  int p0 = blockIdx.x * 64, c0 = blockIdx.y * 64;
  int b = p0 / HW, hw0 = p0 % HW;
  int tid = threadIdx.x;
  for (int e = tid; e < 512; e += 256) {
    int px = e >> 3, cc = e & 7;
    uint4 v = *(const uint4*)&inp[(size_t)(p0 + px) * CP + c0 + cc * 8];
    unsigned short* ps = (unsigned short*)&v;
#pragma unroll
    for (int j = 0; j < 8; ++j) sls[px][cc * 8 + j] = bf2f(ps[j]);
  }
  __syncthreads();
  for (int e = tid; e < 1024; e += 256) {
    int ch = e >> 4, pq = e & 15;
    if (c0 + ch < CO) {
      float4 v;
      v.x = sls[pq * 4 + 0][ch];
      v.y = sls[pq * 4 + 1][ch];
      v.z = sls[pq * 4 + 2][ch];
      v.w = sls[pq * 4 + 3][ch];
      *(float4*)&outp[(size_t)(b * CT + c0 + ch) * HW + hw0 + pq * 4] = v;
    }
  }
}

// ---------------- MFMA implicit-GEMM conv (NHWC bf16 in/out) ------------------
// Block: 256 px (16x16 spatial) x 64 oc. 4 waves, each 64px x 64oc.
// A-frag: m=lane&15 (=tx), k=(lane>>4)*8+j.  B-frag: n=lane&15 (=oc), same k.
// C/D:    col(oc)=lane&15, row(px)=(lane>>4)*4+reg.  [m89/m120-verified]
template <int KS, int PAD, int CINP>
__global__ __launch_bounds__(256) void mfma_conv(
    const unsigned short* __restrict__ xin,
    const unsigned short* __restrict__ wpk, const float* __restrict__ bias,
    unsigned short* __restrict__ yout, int H, int W, int Cout, int OCP, int CT,
    int coff) {
  constexpr int YP = 16 + KS - 1, XP = 16 + KS - 1;
  constexpr int K2 = KS * KS;
  constexpr int SX = 4 * YP * XP * 8;  // ushorts
  constexpr int SW = K2 * 4 * 64 * 8;
  constexpr int SMEM = (SX + SW) > 16384 ? (SX + SW) : 16384;
  __shared__ __align__(16) unsigned short smem[SMEM];

  const int tid = threadIdx.x;
  const int wave = tid >> 6, lane = tid & 63;
  const int l15 = lane & 15, lq = lane >> 4;

  const int tilesX = W >> 4;
  const int perB = (H >> 4) * tilesX;
  const int t = blockIdx.x;
  const int b = t / perB;
  const int r0 = t % perB;
  const int ty0 = (r0 / tilesX) << 4;
  const int tx0 = (r0 % tilesX) << 4;
  const int oc0 = blockIdx.y << 6;
  const int icq_stride = CINP / 8;

  f32x4 acc[4][4];
#pragma unroll
  for (int mf = 0; mf < 4; ++mf)
#pragma unroll
    for (int nf = 0; nf < 4; ++nf) acc[mf][nf] = (f32x4){0.f, 0.f, 0.f, 0.f};

  int baseA[4];
#pragma unroll
  for (int mf = 0; mf < 4; ++mf)
    baseA[mf] = ((lq * YP + wave * 4 + mf) * XP + l15) * 8;
  const int baseB = SX + (lq * 64 + l15) * 8;

  for (int icb = 0; icb < CINP / 32; ++icb) {
    const int ic0 = icb * 32;
    for (int e = tid; e < 4 * YP * XP; e += 256) {
      int q = e / (YP * XP), r = e % (YP * XP);
      int py = r / XP, px = r % XP;
      int gy = ty0 + py - PAD, gx = tx0 + px - PAD;
      uint4 v = make_uint4(0, 0, 0, 0);
      if (gy >= 0 && gy < H && gx >= 0 && gx < W)
        v = *(const uint4*)&xin[(size_t)((b * H + gy) * W + gx) * CINP + ic0 +
                                q * 8];
      *(uint4*)&smem[e * 8] = v;
    }
    for (int e = tid; e < K2 * 256; e += 256) {
      int tap = e >> 8, r = e & 255;
      int q = r >> 6, oc = r & 63;
      uint4 v = *(const uint4*)&wpk[(size_t)((tap * icq_stride + (ic0 >> 3) + q) *
                                                 OCP +
                                             oc0 + oc) *
                                    8];
      *(uint4*)&smem[SX + e * 8] = v;
    }
    __syncthreads();
#pragma unroll
    for (int tap = 0; tap < K2; ++tap) {
      const int dy = tap / KS, dx = tap % KS;
      bf16x8 va[4], vb[4];
#pragma unroll
      for (int mf = 0; mf < 4; ++mf)
        va[mf] = *(const bf16x8*)&smem[baseA[mf] + (dy * XP + dx) * 8];
#pragma unroll
      for (int nf = 0; nf < 4; ++nf)
        vb[nf] = *(const bf16x8*)&smem[baseB + tap * 2048 + nf * 128];
#pragma unroll
      for (int mf = 0; mf < 4; ++mf)
#pragma unroll
        for (int nf = 0; nf < 4; ++nf)
          acc[mf][nf] = __builtin_amdgcn_mfma_f32_16x16x32_bf16(
              va[mf], vb[nf], acc[mf][nf], 0, 0, 0);
    }
    __syncthreads();
  }

  // epilogue: bias+relu, per-wave LDS transpose to [px][oc] bf16, 16B stores
  float bsv[4];
#pragma unroll
  for (int nf = 0; nf < 4; ++nf) {
    int oc = oc0 + nf * 16 + l15;
    bsv[nf] = (oc < Cout) ? bias[oc] : 0.f;
  }
  unsigned short* slice = smem + wave * 4096;
#pragma unroll
  for (int mf = 0; mf < 4; ++mf)
#pragma unroll
    for (int nf = 0; nf < 4; ++nf)
#pragma unroll
      for (int r = 0; r < 4; ++r) {
        int pxl = mf * 16 + lq * 4 + r;
        int ocl = nf * 16 + l15;
        slice[pxl * 64 + ocl] = f2bf(fmaxf(acc[mf][nf][r] + bsv[nf], 0.f));
      }
  // same-wave LDS write->read: compiler inserts lgkmcnt wait (aliasing)
#pragma unroll
  for (int i = 0; i < 8; ++i) {
    int pxl = i * 8 + (lane >> 3);
    int ocq = (lane & 7) * 8;
    uint4 v = *(uint4*)&slice[pxl * 64 + ocq];
    int pxg = wave * 64 + pxl;
    int gy = ty0 + (pxg >> 4), gx = tx0 + (pxg & 15);
    *(uint4*)&yout[(size_t)((b * H + gy) * W + gx) * CT + coff + oc0 + ocq] = v;
  }
}

// ---------------- fp32 direct conv for convf1 (Cin=2, 7x7), bf16-NHWC out ----
#define TOC 64
template <int CIN, int KS, int PAD, int ICB, int TH, int TW, int XCP>
__global__ __launch_bounds__(256) void conv_relu_nhwc(
    const float* __restrict__ x, const float* __restrict__ wt,
    const float* __restrict__ bias, unsigned short* __restrict__ y, int B,
    int H, int W, int Cout, int CT) {
  constexpr int XR = TH + KS - 1;
  constexpr int XC = TW + KS - 1;
  constexpr int K2 = KS * KS;
  constexpr int QPR = TW / 4;

  __shared__ __align__(16) float sx[ICB][XR][XCP];
  __shared__ __align__(16) float sw[ICB][K2][TOC];

  const int nOC = Cout / TOC;
  const int b = blockIdx.z / nOC;
  const int oc0 = (blockIdx.z % nOC) * TOC;
  const int x0 = blockIdx.x * TW;
  const int y0 = blockIdx.y * TH;

  const int tid = threadIdx.x;
  const int oslot = tid >> 5;
  const int pslot = tid & 31;
  const int pr = pslot / QPR;
  const int pq = pslot % QPR;

  float acc[4][8];
#pragma unroll
  for (int p = 0; p < 4; ++p)
#pragma unroll
    for (int o = 0; o < 8; ++o) acc[p][o] = 0.f;

  for (int c0 = 0; c0 < CIN; c0 += ICB) {
    constexpr int XN = ICB * XR * XC;
    for (int e = tid; e < XN; e += 256) {
      int col = e % XC;
      int t = e / XC;
      int row = t % XR;
      int ic = t / XR;
      int gy = y0 + row - PAD;
      int gx = x0 + col - PAD;
      float v = 0.f;
      if (gy >= 0 && gy < H && gx >= 0 && gx < W)
        v = x[((b * CIN + c0 + ic) * H + gy) * W + gx];
      sx[ic][row][col] = v;
    }
    constexpr int WN = ICB * K2 * TOC;
    for (int e = tid; e < WN; e += 256) {
      int oc = e % TOC;
      int t = e / TOC;
      int tap = t % K2;
      int ic = t / K2;
      sw[ic][tap][oc] = wt[((c0 + ic) * K2 + tap) * Cout + oc0 + oc];
    }
    __syncthreads();
#pragma unroll 1
    for (int ic = 0; ic < ICB; ++ic) {
#pragma unroll
      for (int ky = 0; ky < KS; ++ky) {
        float xr[4 + KS - 1];
#pragma unroll
        for (int i = 0; i < 4 + KS - 1; ++i)
          xr[i] = sx[ic][pr + ky][pq * 4 + i];
#pragma unroll
        for (int kx = 0; kx < KS; ++kx) {
          const float4* wp = (const float4*)&sw[ic][ky * KS + kx][oslot * 8];
          float4 w0 = wp[0], w1 = wp[1];
          float wv[8] = {w0.x, w0.y, w0.z, w0.w, w1.x, w1.y, w1.z, w1.w};
#pragma unroll
          for (int p = 0; p < 4; ++p)
#pragma unroll
            for (int o = 0; o < 8; ++o) acc[p][o] += xr[p + kx] * wv[o];
        }
      }
    }
    __syncthreads();
  }

  const int ocb = oc0 + oslot * 8;
  const int oy = y0 + pr;
  const int ox = x0 + pq * 4;
#pragma unroll
  for (int p = 0; p < 4; ++p) {
    unsigned short pk[8];
#pragma unroll
    for (int o = 0; o < 8; ++o)
      pk[o] = f2bf(fmaxf(acc[p][o] + bias[ocb + o], 0.f));
    *(uint4*)&y[(size_t)((b * H + oy) * W + ox + p) * CT + ocb] = *(uint4*)pk;
  }
}

__global__ __launch_bounds__(256) void copy_flow(const float* __restrict__ flow,
                                                 float* __restrict__ out, int B,
                                                 int HW) {
  int q = HW / 4;
  int n = B * 2 * q;
  int i = blockIdx.x * blockDim.x + threadIdx.x;
  if (i < n) {
    float4 v = ((const float4*)flow)[i];
    int p = i % q;
    int t = i / q;
    int c = t % 2;
    int bb = t / 2;
    ((float4*)out)[((bb * 128 + 126 + c) * HW) / 4 + p] = v;
  }
}

extern "C" void kernel_launch(void* const* d_in, const int* in_sizes, int n_in,
                              void* d_out, int out_size, void* d_ws,
                              size_t ws_size, hipStream_t stream) {
  const float* flow = (const float*)d_in[0];
  const float* corr = (const float*)d_in[1];
  const float* wc1 = (const float*)d_in[2];
  const float* bc1 = (const float*)d_in[3];
  const float* wc2 = (const float*)d_in[4];
  const float* bc2 = (const float*)d_in[5];
  const float* wf1 = (const float*)d_in[6];
  const float* bf1 = (const float*)d_in[7];
  const float* wf2 = (const float*)d_in[8];
  const float* bf2 = (const float*)d_in[9];
  const float* wo = (const float*)d_in[10];
  const float* bo = (const float*)d_in[11];
  float* out = (float*)d_out;

  const int B = 8, H = 96, W = 128;
  const int HW = H * W;  // 12288
  const size_t NPX = (size_t)B * HW;  // 98304

  char* ws = (char*)d_ws;
  // region A (69,206,016 B): corrT [NPX][352]bf16; later cat [NPX][256]bf16
  unsigned short* corrT = (unsigned short*)(ws + 0);
  unsigned short* cat = (unsigned short*)(ws + 0);
  // region B (50,331,648 B): buf1 [NPX][256]bf16; later out5/flo1
  unsigned short* buf1 = (unsigned short*)(ws + 69206016);
  unsigned short* out5 = (unsigned short*)(ws + 69206016);            // 25 MB
  unsigned short* flo1 = (unsigned short*)(ws + 69206016 + 25165824); // 25 MB
  // weights
  float* wf1t = (float*)(ws + 119537664);            // [2][49][128] f32
  unsigned short* p1 = (unsigned short*)(ws + 119587840);  // [1][44][256][8]
  unsigned short* p2 = (unsigned short*)(ws + 119768064);  // [9][32][192][8]
  unsigned short* p3 = (unsigned short*)(ws + 120652800);  // [9][16][64][8]
  unsigned short* p4 = (unsigned short*)(ws + 120800256);  // [9][32][128][8]

  // weight repacks
  repack_w<<<dim3(32), dim3(256), 0, stream>>>(wf1, wf1t, 128, 2, 49);
  repack_w_bf16<<<dim3(128), dim3(256), 0, stream>>>(wc1, p1, 256, 324, 1, 44, 256);
  repack_w_bf16<<<dim3(256), dim3(256), 0, stream>>>(wc2, p2, 192, 256, 9, 32, 192);
  repack_w_bf16<<<dim3(64), dim3(256), 0, stream>>>(wf2, p3, 64, 128, 9, 16, 64);
  repack_w_bf16<<<dim3(192), dim3(256), 0, stream>>>(wo, p4, 126, 256, 9, 32, 128);

  // corr NCHW f32 -> NHWC bf16 padded to 352
  nchw2nhwc_bf16<<<dim3(NPX / 64, 6), dim3(256), 0, stream>>>(corr, corrT, 324,
                                                              352, HW);
  // conv1: 1x1 324(352)->256, corrT -> buf1
  mfma_conv<1, 0, 352><<<dim3(384, 4), dim3(256), 0, stream>>>(
      corrT, p1, bc1, buf1, H, W, 256, 256, 256, 0);
  // conv2: 3x3 256->192, buf1 -> cat ch 0..191
  mfma_conv<3, 1, 256><<<dim3(384, 3), dim3(256), 0, stream>>>(
      buf1, p2, bc2, cat, H, W, 192, 192, 256, 0);
  // convf1: 7x7 2->128 fp32 direct, flow -> flo1 (NHWC bf16)
  conv_relu_nhwc<2, 7, 3, 2, 8, 16, 23>
      <<<dim3(8, 12, 16), dim3(256), 0, stream>>>(flow, wf1t, bf1, flo1, B, H,
                                                  W, 128, 128);
  // convf2: 3x3 128->64, flo1 -> cat ch 192..255
  mfma_conv<3, 1, 128><<<dim3(384, 1), dim3(256), 0, stream>>>(
      flo1, p3, bf2, cat, H, W, 64, 64, 256, 192);
  // conv5: 3x3 256->126(128), cat -> out5
  mfma_conv<3, 1, 256><<<dim3(384, 2), dim3(256), 0, stream>>>(
      cat, p4, bo, out5, H, W, 126, 128, 128, 0);
  // out5 NHWC bf16 -> out NCHW f32 (ch 0..125), then flow -> ch 126..127
  nhwc_bf16_2nchw<<<dim3(NPX / 64, 2), dim3(256), 0, stream>>>(out5, out, 128,
                                                               126, 128, HW);
  copy_flow<<<dim3(192), dim3(256), 0, stream>>>(flow, out, B, HW);
}

// Round 4
// 592.075 us; speedup vs baseline: 5.0729x; 1.1371x over previous
//
#include <hip/hip_runtime.h>

// BasicMotionEncoder (RAFT): B=8, H=96, W=128, CORR=324.
// Round 4 = Round 3 + fix: B-fragment global loads were missing the per-lane
// n-offset (l15) -> every 16-block of output channels used channel 0's
// weights. All B-load sites now include "+ l15".
//  - 1x1 path (conv1, convf1-as-im2col): A and B straight from global, no LDS
//    staging, no barriers.
//  - 3x3 path (conv2, convf2, conv5): A staged via global_load_lds(16B) into
//    LDS (9-tap reuse), B straight from global (L1-served), halo-padded
//    inputs so staging has zero bounds checks.

typedef __bf16 bf16x8 __attribute__((ext_vector_type(8)));
typedef float f32x4 __attribute__((ext_vector_type(4)));

__device__ __forceinline__ unsigned short f2bf(float f) {
  __bf16 h = (__bf16)f;
  return __builtin_bit_cast(unsigned short, h);
}
__device__ __forceinline__ float bf2f(unsigned short u) {
  __bf16 h = __builtin_bit_cast(__bf16, u);
  return (float)h;
}

__device__ __forceinline__ void gload_lds16(const unsigned short* g,
                                            unsigned short* l) {
  __builtin_amdgcn_global_load_lds(
      (const __attribute__((address_space(1))) unsigned int*)g,
      (__attribute__((address_space(3))) unsigned int*)l, 16, 0, 0);
}

// ---------------- weight repack: OIHW f32 -> [tap][icq][OCP][8] bf16 ---------
__global__ __launch_bounds__(256) void repack_w_bf16(
    const float* __restrict__ w, unsigned short* __restrict__ dst, int O, int I,
    int K2, int ICQ, int OCP) {
  int n = K2 * ICQ * OCP * 8;
  for (int s = blockIdx.x * 256 + threadIdx.x; s < n; s += gridDim.x * 256) {
    int j = s & 7;
    int r = s >> 3;
    int oc = r % OCP;
    r /= OCP;
    int icq = r % ICQ;
    int tap = r / ICQ;
    int ic = icq * 8 + j;
    float v = (oc < O && ic < I) ? w[((size_t)oc * I + ic) * K2 + tap] : 0.f;
    dst[s] = f2bf(v);
  }
}

// wf1 [128][2][7][7] -> [kq=16][128][8], k = ic*49 + dy*7 + dx, pad 98->128
__global__ __launch_bounds__(256) void repack_wf1(const float* __restrict__ w,
                                                  unsigned short* __restrict__ dst) {
  int s = blockIdx.x * 256 + threadIdx.x;
  if (s >= 16384) return;
  int j = s & 7;
  int oc = (s >> 3) & 127;
  int kq = s >> 10;
  int k = kq * 8 + j;
  float v = 0.f;
  if (k < 98) {
    int ic = k / 49;
    int tap = k - ic * 49;
    v = w[(oc * 2 + ic) * 49 + tap];
  }
  dst[s] = f2bf(v);
}

// ------------- NCHW f32 -> NHWC bf16 (zero-padded channels) ------------------
__global__ __launch_bounds__(256) void nchw2nhwc_bf16(
    const float* __restrict__ in, unsigned short* __restrict__ outp, int C,
    int CP, int HW) {
  __shared__ float sls[64][65];
  int p0 = blockIdx.x * 64;
  int c0 = blockIdx.y * 64;
  int b = p0 / HW, hw0 = p0 % HW;
  int tid = threadIdx.x;
  for (int e = tid; e < 4096; e += 256) {
    int ch = e >> 6, px = e & 63;
    float v = 0.f;
    if (c0 + ch < C) v = in[(size_t)(b * C + c0 + ch) * HW + hw0 + px];
    sls[px][ch] = v;
  }
  __syncthreads();
  for (int e = tid; e < 512; e += 256) {
    int px = e >> 3, cc = e & 7;
    if (c0 + cc * 8 < CP) {
      unsigned short pk[8];
#pragma unroll
      for (int j = 0; j < 8; ++j) pk[j] = f2bf(sls[px][cc * 8 + j]);
      *(uint4*)&outp[(size_t)(p0 + px) * CP + c0 + cc * 8] = *(uint4*)pk;
    }
  }
}

// ------------- NHWC bf16 -> NCHW f32 (channels < CO only) --------------------
__global__ __launch_bounds__(256) void nhwc_bf16_2nchw(
    const unsigned short* __restrict__ inp, float* __restrict__ outp, int CP,
    int CO, int CT, int HW) {
  __shared__ float sls[64][65];
  int p0 = blockIdx.x * 64, c0 = blockIdx.y * 64;
  int b = p0 / HW, hw0 = p0 % HW;
  int tid = threadIdx.x;
  for (int e = tid; e < 512; e += 256) {
    int px = e >> 3, cc = e & 7;
    uint4 v = *(const uint4*)&inp[(size_t)(p0 + px) * CP + c0 + cc * 8];
    unsigned short* ps = (unsigned short*)&v;
#pragma unroll
    for (int j = 0; j < 8; ++j) sls[px][cc * 8 + j] = bf2f(ps[j]);
  }
  __syncthreads();
  for (int e = tid; e < 1024; e += 256) {
    int ch = e >> 4, pq = e & 15;
    if (c0 + ch < CO) {
      float4 v;
      v.x = sls[pq * 4 + 0][ch];
      v.y = sls[pq * 4 + 1][ch];
      v.z = sls[pq * 4 + 2][ch];
      v.w = sls[pq * 4 + 3][ch];
      *(float4*)&outp[(size_t)(b * CT + c0 + ch) * HW + hw0 + pq * 4] = v;
    }
  }
}

// ------------- zero the 1-px halo border of the 3 padded buffers -------------
// buffers: [8][98][130][C] bf16. border px per batch: 2*130 + 2*96 = 452.
__global__ __launch_bounds__(256) void zero_halo3(unsigned short* b0,
                                                  unsigned short* b1,
                                                  unsigned short* b2) {
  unsigned short* bufs[3] = {b0, b1, b2};
  const int Cs[3] = {256, 256, 128};
  unsigned short* buf = bufs[blockIdx.y];
  const int C = Cs[blockIdx.y];
  const int cq = C >> 3;
  int n = 8 * 452 * cq;
  int i = blockIdx.x * 256 + threadIdx.x;
  if (i >= n) return;
  int c = i % cq;
  int t = i / cq;
  int bp = t % 452;
  int bb = t / 452;
  int y, x;
  if (bp < 130) { y = 0; x = bp; }
  else if (bp < 260) { y = 97; x = bp - 130; }
  else { int r = bp - 260; y = 1 + (r >> 1); x = (r & 1) ? 129 : 0; }
  *(uint4*)&buf[((size_t)(bb * 98 + y) * 130 + x) * C + c * 8] =
      make_uint4(0, 0, 0, 0);
}

// ------------- im2col of flow: [8][2][96][128] f32 -> [NPX][128] bf16 --------
// k = ic*49 + dy*7 + dx (k<98), zero-padded to 128.
__global__ __launch_bounds__(256) void im2col_flow(const float* __restrict__ f,
                                                   unsigned short* __restrict__ o,
                                                   int H, int W) {
  int s = blockIdx.x * 256 + threadIdx.x;  // over NPX*16
  int kq = s & 15;
  int px = s >> 4;
  int HW = H * W;
  int b = px / HW;
  int r = px % HW;
  int y = r / W;
  int x = r % W;
  unsigned short pk[8];
#pragma unroll
  for (int j = 0; j < 8; ++j) {
    int k = kq * 8 + j;
    float v = 0.f;
    if (k < 98) {
      int ic = k / 49;
      int t = k - ic * 49;
      int dy = t / 7, dx = t - dy * 7;
      int yy = y + dy - 3, xx = x + dx - 3;
      if (yy >= 0 && yy < H && xx >= 0 && xx < W)
        v = f[((size_t)(b * 2 + ic) * H + yy) * W + xx];
    }
    pk[j] = f2bf(v);
  }
  *(uint4*)&o[(size_t)px * 128 + kq * 8] = *(uint4*)pk;
}

// =================== 1x1 MFMA GEMM (no LDS staging, no barriers) =============
// Block: 256 px (16x16 tile) x 64 oc; 4 waves x (64px x 64oc).
// A-frag: m=lane&15, k=(lane>>4)*8+j.  B-frag: n=lane&15 (=+l15 in oc!).
template <int CINP>
__global__ __launch_bounds__(256) void mfma_gemm(
    const unsigned short* __restrict__ xin,  // [B*H*W][CINP]
    const unsigned short* __restrict__ wpk,  // [CINP/8][OCP][8]
    const float* __restrict__ bias, unsigned short* __restrict__ yout,
    int H, int W, int Cout, int OCP, int CT, int coff, int Wo, int oh) {
  __shared__ __align__(16) unsigned short smem[16384];
  const int tid = threadIdx.x;
  const int wave = tid >> 6, lane = tid & 63;
  const int l15 = lane & 15, lq = lane >> 4;
  const int tilesX = W >> 4;
  const int perB = (H >> 4) * tilesX;
  const int b = blockIdx.x / perB;
  const int r0 = blockIdx.x % perB;
  const int ty0 = (r0 / tilesX) << 4;
  const int tx0 = (r0 % tilesX) << 4;
  const int oc0 = blockIdx.y << 6;

  f32x4 acc[4][4];
#pragma unroll
  for (int mf = 0; mf < 4; ++mf)
#pragma unroll
    for (int nf = 0; nf < 4; ++nf) acc[mf][nf] = (f32x4){0.f, 0.f, 0.f, 0.f};

  size_t rowA[4];
#pragma unroll
  for (int mf = 0; mf < 4; ++mf)
    rowA[mf] =
        ((size_t)(b * H + ty0 + wave * 4 + mf) * W + tx0 + l15) * CINP + lq * 8;

  constexpr int NI = CINP / 32;
  bf16x8 va[4], vb[4];
#pragma unroll
  for (int mf = 0; mf < 4; ++mf) va[mf] = *(const bf16x8*)&xin[rowA[mf]];
#pragma unroll
  for (int nf = 0; nf < 4; ++nf)
    vb[nf] =
        *(const bf16x8*)&wpk[((size_t)lq * OCP + oc0 + l15) * 8 + nf * 128];

#pragma unroll 1
  for (int icb = 0; icb < NI; ++icb) {
    bf16x8 na[4], nb[4];
    const int nx = (icb + 1 < NI) ? icb + 1 : icb;
#pragma unroll
    for (int mf = 0; mf < 4; ++mf)
      na[mf] = *(const bf16x8*)&xin[rowA[mf] + nx * 32];
#pragma unroll
    for (int nf = 0; nf < 4; ++nf)
      nb[nf] = *(const bf16x8*)&wpk[((size_t)(nx * 4 + lq) * OCP + oc0 + l15) *
                                        8 +
                                    nf * 128];
#pragma unroll
    for (int mf = 0; mf < 4; ++mf)
#pragma unroll
      for (int nf = 0; nf < 4; ++nf)
        acc[mf][nf] = __builtin_amdgcn_mfma_f32_16x16x32_bf16(
            va[mf], vb[nf], acc[mf][nf], 0, 0, 0);
#pragma unroll
    for (int mf = 0; mf < 4; ++mf) va[mf] = na[mf];
#pragma unroll
    for (int nf = 0; nf < 4; ++nf) vb[nf] = nb[nf];
  }

  // epilogue: bias+relu, per-wave LDS transpose, 16B stores
  float bsv[4];
#pragma unroll
  for (int nf = 0; nf < 4; ++nf) {
    int oc = oc0 + nf * 16 + l15;
    bsv[nf] = (oc < Cout) ? bias[oc] : 0.f;
  }
  unsigned short* slice = smem + wave * 4096;
#pragma unroll
  for (int mf = 0; mf < 4; ++mf)
#pragma unroll
    for (int nf = 0; nf < 4; ++nf)
#pragma unroll
      for (int r = 0; r < 4; ++r)
        slice[(mf * 16 + lq * 4 + r) * 64 + nf * 16 + l15] =
            f2bf(fmaxf(acc[mf][nf][r] + bsv[nf], 0.f));
  const int Ho = H + 2 * oh;
#pragma unroll
  for (int i = 0; i < 8; ++i) {
    int pxl = i * 8 + (lane >> 3);
    int ocq = (lane & 7) * 8;
    uint4 v = *(uint4*)&slice[pxl * 64 + ocq];
    int pxg = wave * 64 + pxl;
    int gy = ty0 + (pxg >> 4) + oh, gx = tx0 + (pxg & 15) + oh;
    *(uint4*)&yout[((size_t)(b * Ho + gy) * Wo + gx) * CT + coff + oc0 + ocq] = v;
  }
}

// =================== 3x3 MFMA conv (halo input, LDS A, global B) =============
template <int CINP>
__global__ __launch_bounds__(256) void mfma_conv3(
    const unsigned short* __restrict__ xin,  // [B][H+2][W+2][CINP] halo
    const unsigned short* __restrict__ wpk,  // [9][CINP/8][OCP][8]
    const float* __restrict__ bias, unsigned short* __restrict__ yout,
    int H, int W, int Cout, int OCP, int CT, int coff, int Wo, int oh) {
  const int Hp = H + 2, Wp = W + 2;
  constexpr int ICQS = CINP / 8;
  __shared__ __align__(16) unsigned short smem[16384];

  const int tid = threadIdx.x;
  const int wave = tid >> 6, lane = tid & 63;
  const int l15 = lane & 15, lq = lane >> 4;
  const int tilesX = W >> 4;
  const int perB = (H >> 4) * tilesX;
  const int b = blockIdx.x / perB;
  const int r0 = blockIdx.x % perB;
  const int ty0 = (r0 / tilesX) << 4;
  const int tx0 = (r0 % tilesX) << 4;
  const int oc0 = blockIdx.y << 6;

  f32x4 acc[4][4];
#pragma unroll
  for (int mf = 0; mf < 4; ++mf)
#pragma unroll
    for (int nf = 0; nf < 4; ++nf) acc[mf][nf] = (f32x4){0.f, 0.f, 0.f, 0.f};

  const size_t rowbase = (size_t)(b * Hp + ty0) * Wp + tx0;

  for (int icb = 0; icb < CINP / 32; ++icb) {
    const int ic0 = icb * 32;
    // stage 18x18 x 32ic patch: 1296 16B-chunks, LDS dest = e*16 (lane-linear)
#pragma unroll
    for (int k = 0; k < 6; ++k) {
      int e = tid + k * 256;
      if (e < 1296) {
        int q = e / 324;
        int r2 = e - q * 324;
        int py = r2 / 18;
        int px = r2 - py * 18;
        gload_lds16(
            &xin[(rowbase + (size_t)py * Wp + px) * CINP + ic0 + q * 8],
            &smem[e * 8]);
      }
    }
    __syncthreads();

    const unsigned short* wb =
        wpk + ((size_t)(icb * 4 + lq) * OCP + oc0 + l15) * 8;
    bf16x8 vb[4];
#pragma unroll
    for (int nf = 0; nf < 4; ++nf) vb[nf] = *(const bf16x8*)&wb[nf * 128];
#pragma unroll 1
    for (int tap = 0; tap < 9; ++tap) {
      const int dy = tap / 3, dx = tap - dy * 3;
      const int nt = (tap < 8) ? tap + 1 : 8;
      const unsigned short* wn = wb + (size_t)nt * ICQS * OCP * 8;
      bf16x8 nb[4];
#pragma unroll
      for (int nf = 0; nf < 4; ++nf) nb[nf] = *(const bf16x8*)&wn[nf * 128];
      bf16x8 va[4];
#pragma unroll
      for (int mf = 0; mf < 4; ++mf)
        va[mf] = *(const bf16x8*)
            &smem[((lq * 18 + wave * 4 + mf + dy) * 18 + l15 + dx) * 8];
#pragma unroll
      for (int mf = 0; mf < 4; ++mf)
#pragma unroll
        for (int nf = 0; nf < 4; ++nf)
          acc[mf][nf] = __builtin_amdgcn_mfma_f32_16x16x32_bf16(
              va[mf], vb[nf], acc[mf][nf], 0, 0, 0);
#pragma unroll
      for (int nf = 0; nf < 4; ++nf) vb[nf] = nb[nf];
    }
    __syncthreads();
  }

  float bsv[4];
#pragma unroll
  for (int nf = 0; nf < 4; ++nf) {
    int oc = oc0 + nf * 16 + l15;
    bsv[nf] = (oc < Cout) ? bias[oc] : 0.f;
  }
  unsigned short* slice = smem + wave * 4096;
#pragma unroll
  for (int mf = 0; mf < 4; ++mf)
#pragma unroll
    for (int nf = 0; nf < 4; ++nf)
#pragma unroll
      for (int r = 0; r < 4; ++r)
        slice[(mf * 16 + lq * 4 + r) * 64 + nf * 16 + l15] =
            f2bf(fmaxf(acc[mf][nf][r] + bsv[nf], 0.f));
  const int Ho = H + 2 * oh;
#pragma unroll
  for (int i = 0; i < 8; ++i) {
    int pxl = i * 8 + (lane >> 3);
    int ocq = (lane & 7) * 8;
    uint4 v = *(uint4*)&slice[pxl * 64 + ocq];
    int pxg = wave * 64 + pxl;
    int gy = ty0 + (pxg >> 4) + oh, gx = tx0 + (pxg & 15) + oh;
    *(uint4*)&yout[((size_t)(b * Ho + gy) * Wo + gx) * CT + coff + oc0 + ocq] = v;
  }
}

__global__ __launch_bounds__(256) void copy_flow(const float* __restrict__ flow,
                                                 float* __restrict__ out, int B,
                                                 int HW) {
  int q = HW / 4;
  int n = B * 2 * q;
  int i = blockIdx.x * blockDim.x + threadIdx.x;
  if (i < n) {
    float4 v = ((const float4*)flow)[i];
    int p = i % q;
    int t = i / q;
    int c = t % 2;
    int bb = t / 2;
    ((float4*)out)[((bb * 128 + 126 + c) * HW) / 4 + p] = v;
  }
}

extern "C" void kernel_launch(void* const* d_in, const int* in_sizes, int n_in,
                              void* d_out, int out_size, void* d_ws,
                              size_t ws_size, hipStream_t stream) {
  const float* flow = (const float*)d_in[0];
  const float* corr = (const float*)d_in[1];
  const float* wc1 = (const float*)d_in[2];
  const float* bc1 = (const float*)d_in[3];
  const float* wc2 = (const float*)d_in[4];
  const float* bc2 = (const float*)d_in[5];
  const float* wf1 = (const float*)d_in[6];
  const float* bf1 = (const float*)d_in[7];
  const float* wf2 = (const float*)d_in[8];
  const float* bf2 = (const float*)d_in[9];
  const float* wo = (const float*)d_in[10];
  const float* bo = (const float*)d_in[11];
  float* out = (float*)d_out;

  const int B = 8, H = 96, W = 128;
  const int HW = H * W;                 // 12288
  const size_t NPX = (size_t)B * HW;    // 98304

  char* ws = (char*)d_ws;
  // R0 (69,206,016 B): corrT [NPX][352] bf16; then cat [8][98][130][256] bf16
  unsigned short* corrT = (unsigned short*)(ws + 0);
  unsigned short* cat = (unsigned short*)(ws + 0);
  // R1 (52,183,040 B): buf1 [8][98][130][256]; then fcol [NPX][128] + out5
  unsigned short* buf1 = (unsigned short*)(ws + 69206016);
  unsigned short* fcol = (unsigned short*)(ws + 69206016);
  unsigned short* out5 = (unsigned short*)(ws + 69206016 + 25165824);
  // R2 (26,091,520 B): flo1 [8][98][130][128]
  unsigned short* flo1 = (unsigned short*)(ws + 121389056);
  // weights
  unsigned short* p1 = (unsigned short*)(ws + 147480576);  // [1][44][256][8]
  unsigned short* p2 = (unsigned short*)(ws + 147660800);  // [9][32][192][8]
  unsigned short* p3 = (unsigned short*)(ws + 148545536);  // [9][16][64][8]
  unsigned short* p4 = (unsigned short*)(ws + 148692992);  // [9][32][128][8]
  unsigned short* pf1 = (unsigned short*)(ws + 149282816); // [16][128][8]

  // weight repacks
  repack_w_bf16<<<dim3(128), dim3(256), 0, stream>>>(wc1, p1, 256, 324, 1, 44, 256);
  repack_w_bf16<<<dim3(256), dim3(256), 0, stream>>>(wc2, p2, 192, 256, 9, 32, 192);
  repack_w_bf16<<<dim3(64), dim3(256), 0, stream>>>(wf2, p3, 64, 128, 9, 16, 64);
  repack_w_bf16<<<dim3(192), dim3(256), 0, stream>>>(wo, p4, 126, 256, 9, 32, 128);
  repack_wf1<<<dim3(64), dim3(256), 0, stream>>>(wf1, pf1);

  // corr NCHW f32 -> dense NHWC bf16 (ch padded 324->352)
  nchw2nhwc_bf16<<<dim3(NPX / 64, 6), dim3(256), 0, stream>>>(corr, corrT, 324,
                                                              352, HW);
  // conv1: 1x1 352->256, corrT -> buf1 (halo write)
  mfma_gemm<352><<<dim3(384, 4), dim3(256), 0, stream>>>(
      corrT, p1, bc1, buf1, H, W, 256, 256, 256, 0, 130, 1);
  // zero halos of buf1, cat, flo1 (corrT dead now; cat aliases it)
  zero_halo3<<<dim3(512, 3), dim3(256), 0, stream>>>(buf1, cat, flo1);
  // conv2: 3x3 256->192, buf1 -> cat ch 0..191
  mfma_conv3<256><<<dim3(384, 3), dim3(256), 0, stream>>>(
      buf1, p2, bc2, cat, H, W, 192, 192, 256, 0, 130, 1);
  // im2col flow (buf1 dead; fcol aliases it)
  im2col_flow<<<dim3(NPX * 16 / 256), dim3(256), 0, stream>>>(flow, fcol, H, W);
  // convf1 as 1x1 GEMM: 128(k)->128, fcol -> flo1 (halo write)
  mfma_gemm<128><<<dim3(384, 2), dim3(256), 0, stream>>>(
      fcol, pf1, bf1, flo1, H, W, 128, 128, 128, 0, 130, 1);
  // convf2: 3x3 128->64, flo1 -> cat ch 192..255
  mfma_conv3<128><<<dim3(384, 1), dim3(256), 0, stream>>>(
      flo1, p3, bf2, cat, H, W, 64, 64, 256, 192, 130, 1);
  // conv5: 3x3 256->126(128), cat -> out5 (dense)
  mfma_conv3<256><<<dim3(384, 2), dim3(256), 0, stream>>>(
      cat, p4, bo, out5, H, W, 126, 128, 128, 0, 128, 0);
  // out5 -> out NCHW f32 ch 0..125; flow -> ch 126..127
  nhwc_bf16_2nchw<<<dim3(NPX / 64, 2), dim3(256), 0, stream>>>(out5, out, 128,
                                                               126, 128, HW);
  copy_flow<<<dim3(192), dim3(256), 0, stream>>>(flow, out, B, HW);
}

// Round 6
// 556.284 us; speedup vs baseline: 5.3992x; 1.0643x over previous
//
#include <hip/hip_runtime.h>

// BasicMotionEncoder (RAFT): B=8, H=96, W=128, CORR=324.
// Round 6 = Round 5 with the LDS-pointer-array compile fix (integer offsets
// instead of {smem, smem+N} array — addrspacecast static-init unsupported).
//  - 3x3 path: double-buffered global_load_lds A-staging (1 barrier/icb),
//    hoisted staging pointers (no div/mod in loop), q-slices padded to 384
//    chunks (wave-aligned for the uniform-base+lane*16 DMA contract),
//    NF output-channel groups per wave reusing each A-fragment.
//  - 1x1 path: NF=8 (128 oc/block), halves activation re-reads.
//  - Two-pass epilogue (LDS transpose) to fit LDS.

typedef __bf16 bf16x8 __attribute__((ext_vector_type(8)));
typedef float f32x4 __attribute__((ext_vector_type(4)));

__device__ __forceinline__ unsigned short f2bf(float f) {
  __bf16 h = (__bf16)f;
  return __builtin_bit_cast(unsigned short, h);
}
__device__ __forceinline__ float bf2f(unsigned short u) {
  __bf16 h = __builtin_bit_cast(__bf16, u);
  return (float)h;
}

__device__ __forceinline__ void gload_lds16(const unsigned short* g,
                                            unsigned short* l) {
  __builtin_amdgcn_global_load_lds(
      (const __attribute__((address_space(1))) unsigned int*)g,
      (__attribute__((address_space(3))) unsigned int*)l, 16, 0, 0);
}

// ---------------- weight repack: OIHW f32 -> [tap][icq][OCP][8] bf16 ---------
__global__ __launch_bounds__(256) void repack_w_bf16(
    const float* __restrict__ w, unsigned short* __restrict__ dst, int O, int I,
    int K2, int ICQ, int OCP) {
  int n = K2 * ICQ * OCP * 8;
  for (int s = blockIdx.x * 256 + threadIdx.x; s < n; s += gridDim.x * 256) {
    int j = s & 7;
    int r = s >> 3;
    int oc = r % OCP;
    r /= OCP;
    int icq = r % ICQ;
    int tap = r / ICQ;
    int ic = icq * 8 + j;
    float v = (oc < O && ic < I) ? w[((size_t)oc * I + ic) * K2 + tap] : 0.f;
    dst[s] = f2bf(v);
  }
}

// wf1 [128][2][7][7] -> [kq=16][128][8], k = ic*49 + dy*7 + dx, pad 98->128
__global__ __launch_bounds__(256) void repack_wf1(const float* __restrict__ w,
                                                  unsigned short* __restrict__ dst) {
  int s = blockIdx.x * 256 + threadIdx.x;
  if (s >= 16384) return;
  int j = s & 7;
  int oc = (s >> 3) & 127;
  int kq = s >> 10;
  int k = kq * 8 + j;
  float v = 0.f;
  if (k < 98) {
    int ic = k / 49;
    int tap = k - ic * 49;
    v = w[(oc * 2 + ic) * 49 + tap];
  }
  dst[s] = f2bf(v);
}

// ------------- NCHW f32 -> NHWC bf16 (zero-padded channels) ------------------
__global__ __launch_bounds__(256) void nchw2nhwc_bf16(
    const float* __restrict__ in, unsigned short* __restrict__ outp, int C,
    int CP, int HW) {
  __shared__ float sls[64][65];
  int p0 = blockIdx.x * 64;
  int c0 = blockIdx.y * 64;
  int b = p0 / HW, hw0 = p0 % HW;
  int tid = threadIdx.x;
  for (int e = tid; e < 4096; e += 256) {
    int ch = e >> 6, px = e & 63;
    float v = 0.f;
    if (c0 + ch < C) v = in[(size_t)(b * C + c0 + ch) * HW + hw0 + px];
    sls[px][ch] = v;
  }
  __syncthreads();
  for (int e = tid; e < 512; e += 256) {
    int px = e >> 3, cc = e & 7;
    if (c0 + cc * 8 < CP) {
      unsigned short pk[8];
#pragma unroll
      for (int j = 0; j < 8; ++j) pk[j] = f2bf(sls[px][cc * 8 + j]);
      *(uint4*)&outp[(size_t)(p0 + px) * CP + c0 + cc * 8] = *(uint4*)pk;
    }
  }
}

// ------------- NHWC bf16 -> NCHW f32 (channels < CO only) --------------------
__global__ __launch_bounds__(256) void nhwc_bf16_2nchw(
    const unsigned short* __restrict__ inp, float* __restrict__ outp, int CP,
    int CO, int CT, int HW) {
  __shared__ float sls[64][65];
  int p0 = blockIdx.x * 64, c0 = blockIdx.y * 64;
  int b = p0 / HW, hw0 = p0 % HW;
  int tid = threadIdx.x;
  for (int e = tid; e < 512; e += 256) {
    int px = e >> 3, cc = e & 7;
    uint4 v = *(const uint4*)&inp[(size_t)(p0 + px) * CP + c0 + cc * 8];
    unsigned short* ps = (unsigned short*)&v;
#pragma unroll
    for (int j = 0; j < 8; ++j) sls[px][cc * 8 + j] = bf2f(ps[j]);
  }
  __syncthreads();
  for (int e = tid; e < 1024; e += 256) {
    int ch = e >> 4, pq = e & 15;
    if (c0 + ch < CO) {
      float4 v;
      v.x = sls[pq * 4 + 0][ch];
      v.y = sls[pq * 4 + 1][ch];
      v.z = sls[pq * 4 + 2][ch];
      v.w = sls[pq * 4 + 3][ch];
      *(float4*)&outp[(size_t)(b * CT + c0 + ch) * HW + hw0 + pq * 4] = v;
    }
  }
}

// ------------- zero the 1-px halo border of the 3 padded buffers -------------
__global__ __launch_bounds__(256) void zero_halo3(unsigned short* b0,
                                                  unsigned short* b1,
                                                  unsigned short* b2) {
  unsigned short* buf = (blockIdx.y == 0) ? b0 : (blockIdx.y == 1) ? b1 : b2;
  const int C = (blockIdx.y == 2) ? 128 : 256;
  const int cq = C >> 3;
  int n = 8 * 452 * cq;
  int i = blockIdx.x * 256 + threadIdx.x;
  if (i >= n) return;
  int c = i % cq;
  int t = i / cq;
  int bp = t % 452;
  int bb = t / 452;
  int y, x;
  if (bp < 130) { y = 0; x = bp; }
  else if (bp < 260) { y = 97; x = bp - 130; }
  else { int r = bp - 260; y = 1 + (r >> 1); x = (r & 1) ? 129 : 0; }
  *(uint4*)&buf[((size_t)(bb * 98 + y) * 130 + x) * C + c * 8] =
      make_uint4(0, 0, 0, 0);
}

// ------------- im2col of flow: [8][2][96][128] f32 -> [NPX][128] bf16 --------
__global__ __launch_bounds__(256) void im2col_flow(const float* __restrict__ f,
                                                   unsigned short* __restrict__ o,
                                                   int H, int W) {
  int s = blockIdx.x * 256 + threadIdx.x;  // over NPX*16
  int kq = s & 15;
  int px = s >> 4;
  int HW = H * W;
  int b = px / HW;
  int r = px % HW;
  int y = r / W;
  int x = r % W;
  unsigned short pk[8];
#pragma unroll
  for (int j = 0; j < 8; ++j) {
    int k = kq * 8 + j;
    float v = 0.f;
    if (k < 98) {
      int ic = k / 49;
      int t = k - ic * 49;
      int dy = t / 7, dx = t - dy * 7;
      int yy = y + dy - 3, xx = x + dx - 3;
      if (yy >= 0 && yy < H && xx >= 0 && xx < W)
        v = f[((size_t)(b * 2 + ic) * H + yy) * W + xx];
    }
    pk[j] = f2bf(v);
  }
  *(uint4*)&o[(size_t)px * 128 + kq * 8] = *(uint4*)pk;
}

// =================== 1x1 MFMA GEMM (no LDS staging, no barriers) =============
// Block: 256 px x NF*16 oc; 4 waves x (64px x NF*16oc).
template <int CINP, int NF>
__global__ __launch_bounds__(256, 2) void mfma_gemm(
    const unsigned short* __restrict__ xin,  // [B*H*W][CINP]
    const unsigned short* __restrict__ wpk,  // [CINP/8][OCP][8]
    const float* __restrict__ bias, unsigned short* __restrict__ yout,
    int H, int W, int Cout, int OCP, int CT, int coff, int Wo, int oh) {
  __shared__ __align__(16) unsigned short smem[NF * 2048];
  const int tid = threadIdx.x;
  const int wave = tid >> 6, lane = tid & 63;
  const int l15 = lane & 15, lq = lane >> 4;
  const int tilesX = W >> 4;
  const int perB = (H >> 4) * tilesX;
  const int b = blockIdx.x / perB;
  const int r0 = blockIdx.x % perB;
  const int ty0 = (r0 / tilesX) << 4;
  const int tx0 = (r0 % tilesX) << 4;
  const int oc0 = blockIdx.y * (NF * 16);

  f32x4 acc[4][NF];
#pragma unroll
  for (int mf = 0; mf < 4; ++mf)
#pragma unroll
    for (int nf = 0; nf < NF; ++nf) acc[mf][nf] = (f32x4){0.f, 0.f, 0.f, 0.f};

  size_t rowA[4];
#pragma unroll
  for (int mf = 0; mf < 4; ++mf)
    rowA[mf] =
        ((size_t)(b * H + ty0 + wave * 4 + mf) * W + tx0 + l15) * CINP + lq * 8;
  const unsigned short* wB = wpk + ((size_t)lq * OCP + oc0 + l15) * 8;
  const int icbStr = 4 * OCP * 8;

  constexpr int NI = CINP / 32;
#pragma unroll 2
  for (int icb = 0; icb < NI; ++icb) {
    bf16x8 va[4], vb[NF];
#pragma unroll
    for (int mf = 0; mf < 4; ++mf)
      va[mf] = *(const bf16x8*)&xin[rowA[mf] + icb * 32];
#pragma unroll
    for (int nf = 0; nf < NF; ++nf)
      vb[nf] = *(const bf16x8*)&wB[icb * icbStr + nf * 128];
#pragma unroll
    for (int mf = 0; mf < 4; ++mf)
#pragma unroll
      for (int nf = 0; nf < NF; ++nf)
        acc[mf][nf] = __builtin_amdgcn_mfma_f32_16x16x32_bf16(
            va[mf], vb[nf], acc[mf][nf], 0, 0, 0);
  }

  // two-pass epilogue: bias+relu, per-wave LDS transpose, 16B stores
  float bsv[NF];
#pragma unroll
  for (int nf = 0; nf < NF; ++nf) {
    int oc = oc0 + nf * 16 + l15;
    bsv[nf] = (oc < Cout) ? bias[oc] : 0.f;
  }
  unsigned short* slice = smem + wave * (NF * 512);
  const int Ho = H + 2 * oh;
#pragma unroll
  for (int pass = 0; pass < 2; ++pass) {
#pragma unroll
    for (int mf = 0; mf < 4; ++mf)
#pragma unroll
      for (int h = 0; h < NF / 2; ++h) {
        const int nf = pass * (NF / 2) + h;
#pragma unroll
        for (int r = 0; r < 4; ++r)
          slice[(mf * 16 + lq * 4 + r) * (NF * 8) + h * 16 + l15] =
              f2bf(fmaxf(acc[mf][nf][r] + bsv[nf], 0.f));
      }
#pragma unroll
    for (int j = 0; j < NF; ++j) {
      int c = j * 64 + lane;
      int pxl = c / NF;
      int ocq = (c - pxl * NF) * 8;
      uint4 v = *(uint4*)&slice[pxl * (NF * 8) + ocq];
      int pxg = wave * 64 + pxl;
      int gy = ty0 + (pxg >> 4) + oh, gx = tx0 + (pxg & 15) + oh;
      *(uint4*)&yout[((size_t)(b * Ho + gy) * Wo + gx) * CT + coff + oc0 +
                     pass * (NF * 8) + ocq] = v;
    }
  }
}

// =================== 3x3 MFMA conv (halo input, dbuf LDS A, global B) ========
// LDS A layout per buffer: chunk index = q*384 + py*18 + px (q-slice padded
// 324->384 = 6 waves of 64 so global_load_lds dest stays base+lane*16).
template <int CINP, int NF>
__global__ __launch_bounds__(256, 2) void mfma_conv3(
    const unsigned short* __restrict__ xin,  // [B][H+2][W+2][CINP] halo
    const unsigned short* __restrict__ wpk,  // [9][CINP/8][OCP][8]
    const float* __restrict__ bias, unsigned short* __restrict__ yout,
    int H, int W, int Cout, int OCP, int CT, int coff, int Wo, int oh) {
  const int Hp = H + 2, Wp = W + 2;
  constexpr int ICQS = CINP / 8;
  constexpr int NI = CINP / 32;
  __shared__ __align__(16) unsigned short smem[24576];  // 2 x 1536 chunks

  const int tid = threadIdx.x;
  const int wave = tid >> 6, lane = tid & 63;
  const int l15 = lane & 15, lq = lane >> 4;
  const int tilesX = W >> 4;
  const int perB = (H >> 4) * tilesX;
  const int b = blockIdx.x / perB;
  const int r0 = blockIdx.x % perB;
  const int ty0 = (r0 / tilesX) << 4;
  const int tx0 = (r0 % tilesX) << 4;
  const int oc0 = blockIdx.y * (NF * 16);

  f32x4 acc[4][NF];
#pragma unroll
  for (int mf = 0; mf < 4; ++mf)
#pragma unroll
    for (int nf = 0; nf < NF; ++nf) acc[mf][nf] = (f32x4){0.f, 0.f, 0.f, 0.f};

  // hoisted staging pointers: thread handles chunks e = tid + k*256
  const size_t rowbase = (size_t)(b * Hp + ty0) * Wp + tx0;
  const unsigned short* gp[6];
#pragma unroll
  for (int k = 0; k < 6; ++k) {
    int e = tid + k * 256;
    int q = e / 384;
    int r = e - q * 384;
    int rc = (r < 324) ? r : 323;  // pad lanes load a harmless valid chunk
    int py = rc / 18, px = rc - py * 18;
    gp[k] = xin + (rowbase + (size_t)py * Wp + px) * CINP + q * 8;
  }
  const unsigned short* wB = wpk + ((size_t)lq * OCP + oc0 + l15) * 8;
  const int icbStr = 4 * OCP * 8;
  const int tapStr = ICQS * OCP * 8;

  // double buffers at integer LDS offsets 0 / 12288 (ushorts)
  // prologue: stage icb 0 into buf 0
#pragma unroll
  for (int k = 0; k < 6; ++k)
    gload_lds16(gp[k], smem + (tid + k * 256) * 8);

  for (int icb = 0; icb < NI; ++icb) {
    const int curOff = (icb & 1) * 12288;
    __syncthreads();  // drains stage(cur); other buf free (read last iter)
    if (icb + 1 < NI) {
      const int nxtOff = curOff ^ 12288;
#pragma unroll
      for (int k = 0; k < 6; ++k)
        gload_lds16(gp[k] + (icb + 1) * 32,
                    smem + nxtOff + (tid + k * 256) * 8);
    }
    const unsigned short* wbi = wB + icb * icbStr;
#pragma unroll
    for (int tap = 0; tap < 9; ++tap) {
      const int dy = tap / 3, dx = tap - dy * 3;
      bf16x8 vb[NF], va[4];
#pragma unroll
      for (int nf = 0; nf < NF; ++nf)
        vb[nf] = *(const bf16x8*)&wbi[tap * tapStr + nf * 128];
#pragma unroll
      for (int mf = 0; mf < 4; ++mf)
        va[mf] = *(const bf16x8*)
            &smem[curOff +
                  (lq * 384 + (wave * 4 + mf + dy) * 18 + l15 + dx) * 8];
#pragma unroll
      for (int mf = 0; mf < 4; ++mf)
#pragma unroll
        for (int nf = 0; nf < NF; ++nf)
          acc[mf][nf] = __builtin_amdgcn_mfma_f32_16x16x32_bf16(
              va[mf], vb[nf], acc[mf][nf], 0, 0, 0);
    }
  }
  __syncthreads();  // epilogue slices overlap A buffers

  float bsv[NF];
#pragma unroll
  for (int nf = 0; nf < NF; ++nf) {
    int oc = oc0 + nf * 16 + l15;
    bsv[nf] = (oc < Cout) ? bias[oc] : 0.f;
  }
  unsigned short* slice = smem + wave * (NF * 512);
  const int Ho = H + 2 * oh;
#pragma unroll
  for (int pass = 0; pass < 2; ++pass) {
#pragma unroll
    for (int mf = 0; mf < 4; ++mf)
#pragma unroll
      for (int h = 0; h < NF / 2; ++h) {
        const int nf = pass * (NF / 2) + h;
#pragma unroll
        for (int r = 0; r < 4; ++r)
          slice[(mf * 16 + lq * 4 + r) * (NF * 8) + h * 16 + l15] =
              f2bf(fmaxf(acc[mf][nf][r] + bsv[nf], 0.f));
      }
#pragma unroll
    for (int j = 0; j < NF; ++j) {
      int c = j * 64 + lane;
      int pxl = c / NF;
      int ocq = (c - pxl * NF) * 8;
      uint4 v = *(uint4*)&slice[pxl * (NF * 8) + ocq];
      int pxg = wave * 64 + pxl;
      int gy = ty0 + (pxg >> 4) + oh, gx = tx0 + (pxg & 15) + oh;
      *(uint4*)&yout[((size_t)(b * Ho + gy) * Wo + gx) * CT + coff + oc0 +
                     pass * (NF * 8) + ocq] = v;
    }
  }
}

__global__ __launch_bounds__(256) void copy_flow(const float* __restrict__ flow,
                                                 float* __restrict__ out, int B,
                                                 int HW) {
  int q = HW / 4;
  int n = B * 2 * q;
  int i = blockIdx.x * blockDim.x + threadIdx.x;
  if (i < n) {
    float4 v = ((const float4*)flow)[i];
    int p = i % q;
    int t = i / q;
    int c = t % 2;
    int bb = t / 2;
    ((float4*)out)[((bb * 128 + 126 + c) * HW) / 4 + p] = v;
  }
}

extern "C" void kernel_launch(void* const* d_in, const int* in_sizes, int n_in,
                              void* d_out, int out_size, void* d_ws,
                              size_t ws_size, hipStream_t stream) {
  const float* flow = (const float*)d_in[0];
  const float* corr = (const float*)d_in[1];
  const float* wc1 = (const float*)d_in[2];
  const float* bc1 = (const float*)d_in[3];
  const float* wc2 = (const float*)d_in[4];
  const float* bc2 = (const float*)d_in[5];
  const float* wf1 = (const float*)d_in[6];
  const float* bf1 = (const float*)d_in[7];
  const float* wf2 = (const float*)d_in[8];
  const float* bf2 = (const float*)d_in[9];
  const float* wo = (const float*)d_in[10];
  const float* bo = (const float*)d_in[11];
  float* out = (float*)d_out;

  const int B = 8, H = 96, W = 128;
  const int HW = H * W;                 // 12288
  const size_t NPX = (size_t)B * HW;    // 98304

  char* ws = (char*)d_ws;
  // R0: corrT [NPX][352] bf16; then cat [8][98][130][256] bf16
  unsigned short* corrT = (unsigned short*)(ws + 0);
  unsigned short* cat = (unsigned short*)(ws + 0);
  // R1: buf1 [8][98][130][256]; then fcol [NPX][128] + out5
  unsigned short* buf1 = (unsigned short*)(ws + 69206016);
  unsigned short* fcol = (unsigned short*)(ws + 69206016);
  unsigned short* out5 = (unsigned short*)(ws + 69206016 + 25165824);
  // R2: flo1 [8][98][130][128]
  unsigned short* flo1 = (unsigned short*)(ws + 121389056);
  // weights
  unsigned short* p1 = (unsigned short*)(ws + 147480576);  // [1][44][256][8]
  unsigned short* p2 = (unsigned short*)(ws + 147660800);  // [9][32][192][8]
  unsigned short* p3 = (unsigned short*)(ws + 148545536);  // [9][16][64][8]
  unsigned short* p4 = (unsigned short*)(ws + 148692992);  // [9][32][128][8]
  unsigned short* pf1 = (unsigned short*)(ws + 149282816); // [16][128][8]

  // weight repacks
  repack_w_bf16<<<dim3(128), dim3(256), 0, stream>>>(wc1, p1, 256, 324, 1, 44, 256);
  repack_w_bf16<<<dim3(256), dim3(256), 0, stream>>>(wc2, p2, 192, 256, 9, 32, 192);
  repack_w_bf16<<<dim3(64), dim3(256), 0, stream>>>(wf2, p3, 64, 128, 9, 16, 64);
  repack_w_bf16<<<dim3(192), dim3(256), 0, stream>>>(wo, p4, 126, 256, 9, 32, 128);
  repack_wf1<<<dim3(64), dim3(256), 0, stream>>>(wf1, pf1);

  // corr NCHW f32 -> dense NHWC bf16 (ch padded 324->352)
  nchw2nhwc_bf16<<<dim3(NPX / 64, 6), dim3(256), 0, stream>>>(corr, corrT, 324,
                                                              352, HW);
  // conv1: 1x1 352->256 (128 oc/block), corrT -> buf1 (halo write)
  mfma_gemm<352, 8><<<dim3(384, 2), dim3(256), 0, stream>>>(
      corrT, p1, bc1, buf1, H, W, 256, 256, 256, 0, 130, 1);
  // zero halos of buf1, cat, flo1 (corrT dead now; cat aliases it)
  zero_halo3<<<dim3(512, 3), dim3(256), 0, stream>>>(buf1, cat, flo1);
  // conv2: 3x3 256->192 (96 oc/block), buf1 -> cat ch 0..191
  mfma_conv3<256, 6><<<dim3(384, 2), dim3(256), 0, stream>>>(
      buf1, p2, bc2, cat, H, W, 192, 192, 256, 0, 130, 1);
  // im2col flow (buf1 dead; fcol aliases it)
  im2col_flow<<<dim3(NPX * 16 / 256), dim3(256), 0, stream>>>(flow, fcol, H, W);
  // convf1 as 1x1 GEMM: 128(k)->128, fcol -> flo1 (halo write)
  mfma_gemm<128, 8><<<dim3(384, 1), dim3(256), 0, stream>>>(
      fcol, pf1, bf1, flo1, H, W, 128, 128, 128, 0, 130, 1);
  // convf2: 3x3 128->64, flo1 -> cat ch 192..255
  mfma_conv3<128, 4><<<dim3(384, 1), dim3(256), 0, stream>>>(
      flo1, p3, bf2, cat, H, W, 64, 64, 256, 192, 130, 1);
  // conv5: 3x3 256->126 (128 oc/block), cat -> out5 (dense)
  mfma_conv3<256, 8><<<dim3(384, 1), dim3(256), 0, stream>>>(
      cat, p4, bo, out5, H, W, 126, 128, 128, 0, 128, 0);
  // out5 -> out NCHW f32 ch 0..125; flow -> ch 126..127
  nhwc_bf16_2nchw<<<dim3(NPX / 64, 2), dim3(256), 0, stream>>>(out5, out, 128,
                                                               126, 128, HW);
  copy_flow<<<dim3(192), dim3(256), 0, stream>>>(flow, out, B, HW);
}